// Round 4
// baseline (321448.413 us; speedup 1.0000x reference)
//
#include <hip/hip_runtime.h>

#define SEQLEN 8192
#define EMB    1024
#define HID    2048
#define NCHARS 256
#define DIN    3072   // EMB + HID
#define R4     8192   // 4*HID

typedef __bf16 bf16x8 __attribute__((ext_vector_type(8)));
typedef float  f32x4  __attribute__((ext_vector_type(4)));

__device__ __forceinline__ unsigned short f2bf(float f) {
    unsigned int u = __float_as_uint(f);
    u = (u + 0x7fffu + ((u >> 16) & 1u)) >> 16;   // RNE
    return (unsigned short)u;
}

__device__ __forceinline__ float bf2f(unsigned short u) {
    return __uint_as_float((unsigned)u << 16);
}

__device__ __forceinline__ float sigmoid_fast(float x) {
    return 1.0f / (1.0f + __expf(-x));
}

__device__ __forceinline__ float tanh_fast(float x) {
    float a = fabsf(x);
    float e = __expf(-2.0f * a);
    float r = (1.0f - e) / (1.0f + e);
    return copysignf(r, x);
}

// ---------------- prep: gather emb rows -> bf16 A, W4 input-cols -> bf16 B ----------------
__global__ __launch_bounds__(256) void prep_a(const int* __restrict__ seq,
                                              const float* __restrict__ emb,
                                              unsigned short* __restrict__ A) {
    const int t = blockIdx.x, k4 = threadIdx.x;          // 256 float4 per row == EMB
    const float4 v = ((const float4*)(emb + (size_t)seq[t] * EMB))[k4];
    ushort4 o;
    o.x = f2bf(v.x); o.y = f2bf(v.y); o.z = f2bf(v.z); o.w = f2bf(v.w);
    ((ushort4*)(A + (size_t)t * EMB))[k4] = o;
}

__global__ __launch_bounds__(256) void prep_b(const float* __restrict__ Wf,
                                              const float* __restrict__ Wi,
                                              const float* __restrict__ Wo,
                                              const float* __restrict__ Wc,
                                              unsigned short* __restrict__ B) {
    const int r = blockIdx.x, k4 = threadIdx.x;          // r = g*2048 + j
    const int g = r >> 11, j = r & 2047;
    const float* W = (g == 0) ? Wf : (g == 1) ? Wi : (g == 2) ? Wo : Wc;
    const float4 v = ((const float4*)(W + (size_t)j * DIN))[k4];   // cols [0,1024)
    ushort4 o;
    o.x = f2bf(v.x); o.y = f2bf(v.y); o.z = f2bf(v.z); o.w = f2bf(v.w);
    ((ushort4*)(B + (size_t)r * EMB))[k4] = o;
}

// ---------------- Zx = A(bf16) @ B(bf16)^T  -> bf16 [8192][8192] ----------------
// m97-style: 128x128 tile, BK=32, 4 waves, 16x16x32 bf16 MFMA, 4x4 frags/wave.
// Fragment maps (m89/m91-verified): A row=lane&15, k=(lane>>4)*8; C/D col=lane&15,
// row=(lane>>4)*4+r.  bg holds Bmat[n][k] == B^T[k][n], so D = A·B^T as required.
// Zx stored bf16: |dz| ~ sigma_z(1.3e-2) * 2^-9 ~ 2.6e-5 — negligible through gates.
__global__ __launch_bounds__(256) void gemm_zx(const unsigned short* __restrict__ A,
                                               const unsigned short* __restrict__ B,
                                               unsigned short* __restrict__ C) {
    constexpr int K = EMB;
    __shared__ __align__(16) unsigned short As[128 * 32];
    __shared__ __align__(16) unsigned short Bs[128 * 32];
    const int m0 = blockIdx.y * 128, n0 = blockIdx.x * 128;
    const int tid = threadIdx.x, lane = tid & 63;
    const int w = tid >> 6, wr = w >> 1, wc = w & 1;
    f32x4 acc[4][4] = {};
    for (int k0 = 0; k0 < K; k0 += 32) {
        __syncthreads();
        #pragma unroll
        for (int s = 0; s < 2; ++s) {
            const int e = (tid + s * 256) * 8;           // linear bf16 elem in 128x32 tile
            const int row = e >> 5, kk = e & 31;
            *(uint4*)&As[e] = *(const uint4*)&A[(size_t)(m0 + row) * K + k0 + kk];
            *(uint4*)&Bs[e] = *(const uint4*)&B[(size_t)(n0 + row) * K + k0 + kk];
        }
        __syncthreads();
        bf16x8 af[4], bg[4];
        #pragma unroll
        for (int mi = 0; mi < 4; ++mi)
            af[mi] = *(const bf16x8*)&As[(wr * 64 + mi * 16 + (lane & 15)) * 32 + (lane >> 4) * 8];
        #pragma unroll
        for (int ni = 0; ni < 4; ++ni)
            bg[ni] = *(const bf16x8*)&Bs[(wc * 64 + ni * 16 + (lane & 15)) * 32 + (lane >> 4) * 8];
        #pragma unroll
        for (int mi = 0; mi < 4; ++mi)
            #pragma unroll
            for (int ni = 0; ni < 4; ++ni)
                acc[mi][ni] = __builtin_amdgcn_mfma_f32_16x16x32_bf16(af[mi], bg[ni], acc[mi][ni], 0, 0, 0);
    }
    #pragma unroll
    for (int mi = 0; mi < 4; ++mi)
        #pragma unroll
        for (int ni = 0; ni < 4; ++ni)
            #pragma unroll
            for (int r = 0; r < 4; ++r)
                C[(size_t)(m0 + wr * 64 + mi * 16 + (lane >> 4) * 4 + r) * R4
                  + (n0 + wc * 64 + ni * 16 + (lane & 15))] = f2bf(acc[mi][ni][r]);
}

// ---------------- persistent sequential LSTM ----------------
// 256 blocks x 512 threads. Block b owns hidden units j = b*8 + w (wave w = tid>>6).
// h-part weights live in VGPRs: wreg[g][q*4+u] = W_g[j][EMB + q*256 + lane*4 + u].
// Per step: wave w waits for its 32 producer blocks' flags >= t, stages segment w of
// h_{t-1} into LDS, block-wide barrier, 128-FMA/lane matvec, 64-lane butterfly reduce,
// gates, lane0 writes h/flag. Safety argument:
//   - Union of the 8 waves' poll sets = ALL 256 flags, and all waves must pass the
//     post-staging __syncthreads() -> a block enters step-t compute only after every
//     block finished step t-1.
//   - flags[X] >= t implies X finished STAGING h_{t-2} (staging precedes the flag
//     store in step t-1), so writing h_t into slot t&1 == (t-2)&1 cannot race readers.
//   - Co-residency: 256 blocks x 8 waves <= 1024 wave-slots even at the 256-VGPR cap
//     (launch_bounds(512,2) -> 2 waves/SIMD) -> no deadlock.
//   - Cross-XCD visibility: agent-scope release store (+threadfence, kept for the
//     first correctness run; candidate to strip) / agent-scope acquire polls.
__global__ __launch_bounds__(512, 2) void lstm_seq(
    const float* __restrict__ Wf, const float* __restrict__ Wi,
    const float* __restrict__ Wo, const float* __restrict__ Wc,
    const float* __restrict__ bfv, const float* __restrict__ biv,
    const float* __restrict__ bov, const float* __restrict__ bcv,
    const unsigned short* __restrict__ Zx, float* __restrict__ Hmat,
    float* __restrict__ hbuf, unsigned* __restrict__ flags,
    float* __restrict__ outH, float* __restrict__ outC)
{
    __shared__ float h_lds[HID];                         // 8 KB
    const int tid = threadIdx.x;
    const int lane = tid & 63;
    const int w = tid >> 6;                              // 0..7
    const int b = blockIdx.x;                            // 0..255
    const int j = b * 8 + w;                             // hidden unit

    // --- load h-part weights into registers (coalesced float4 per lane) ---
    float wreg[4][32];
    {
        const float* Wp[4] = {Wf, Wi, Wo, Wc};
        #pragma unroll
        for (int g = 0; g < 4; ++g) {
            const float* src = Wp[g] + (size_t)j * DIN + EMB;
            #pragma unroll
            for (int q = 0; q < 8; ++q) {
                const float4 v = *(const float4*)(src + q * 256 + lane * 4);
                wreg[g][q * 4 + 0] = v.x; wreg[g][q * 4 + 1] = v.y;
                wreg[g][q * 4 + 2] = v.z; wreg[g][q * 4 + 3] = v.w;
            }
        }
    }
    const float bias0 = bfv[j], bias1 = biv[j], bias2 = bov[j], bias3 = bcv[j];

    float zx0 = bf2f(Zx[(size_t)0 * R4 + 0 * HID + j]);
    float zx1 = bf2f(Zx[(size_t)0 * R4 + 1 * HID + j]);
    float zx2 = bf2f(Zx[(size_t)0 * R4 + 2 * HID + j]);
    float zx3 = bf2f(Zx[(size_t)0 * R4 + 3 * HID + j]);

    float cst = 0.0f, hlast = 0.0f;

    for (int t = 0; t < SEQLEN; ++t) {
        // --- stage h_{t-1} segment w (256 floats) into LDS ---
        if (t == 0) {
            *(float4*)&h_lds[w * 256 + lane * 4] = make_float4(0.f, 0.f, 0.f, 0.f);
        } else {
            const unsigned need = (unsigned)t;
            for (;;) {
                unsigned fv = need;
                if (lane < 32)
                    fv = __hip_atomic_load(&flags[w * 32 + lane], __ATOMIC_ACQUIRE,
                                           __HIP_MEMORY_SCOPE_AGENT);
                if (__all((int)(fv >= need))) break;
                __builtin_amdgcn_s_sleep(1);
            }
            const float4 hv = *(const float4*)&hbuf[((t - 1) & 1) * HID + w * 256 + lane * 4];
            *(float4*)&h_lds[w * 256 + lane * 4] = hv;
        }
        __syncthreads();

        // --- matvec: 128 FMAs/lane, 4 independent accumulator chains ---
        float a0 = 0.f, a1 = 0.f, a2 = 0.f, a3 = 0.f;
        #pragma unroll
        for (int q = 0; q < 8; ++q) {
            const float4 hv = *(const float4*)&h_lds[q * 256 + lane * 4];
            a0 = fmaf(wreg[0][q * 4 + 0], hv.x, a0); a1 = fmaf(wreg[1][q * 4 + 0], hv.x, a1);
            a2 = fmaf(wreg[2][q * 4 + 0], hv.x, a2); a3 = fmaf(wreg[3][q * 4 + 0], hv.x, a3);
            a0 = fmaf(wreg[0][q * 4 + 1], hv.y, a0); a1 = fmaf(wreg[1][q * 4 + 1], hv.y, a1);
            a2 = fmaf(wreg[2][q * 4 + 1], hv.y, a2); a3 = fmaf(wreg[3][q * 4 + 1], hv.y, a3);
            a0 = fmaf(wreg[0][q * 4 + 2], hv.z, a0); a1 = fmaf(wreg[1][q * 4 + 2], hv.z, a1);
            a2 = fmaf(wreg[2][q * 4 + 2], hv.z, a2); a3 = fmaf(wreg[3][q * 4 + 2], hv.z, a3);
            a0 = fmaf(wreg[0][q * 4 + 3], hv.w, a0); a1 = fmaf(wreg[1][q * 4 + 3], hv.w, a1);
            a2 = fmaf(wreg[2][q * 4 + 3], hv.w, a2); a3 = fmaf(wreg[3][q * 4 + 3], hv.w, a3);
        }

        // --- prefetch next step's Zx (HBM latency hidden under reduce/gates/next poll) ---
        float nzx0 = 0.f, nzx1 = 0.f, nzx2 = 0.f, nzx3 = 0.f;
        if (t + 1 < SEQLEN) {
            const size_t base = (size_t)(t + 1) * R4 + j;
            nzx0 = bf2f(Zx[base]);           nzx1 = bf2f(Zx[base + HID]);
            nzx2 = bf2f(Zx[base + 2 * HID]); nzx3 = bf2f(Zx[base + 3 * HID]);
        }

        // --- reduce across the 64 lanes ---
        #pragma unroll
        for (int off = 32; off; off >>= 1) {
            a0 += __shfl_xor(a0, off, 64);
            a1 += __shfl_xor(a1, off, 64);
            a2 += __shfl_xor(a2, off, 64);
            a3 += __shfl_xor(a3, off, 64);
        }

        // --- gates (all lanes redundantly; lane0 stores) ---
        const float zf = zx0 + bias0 + a0;
        const float zi = zx1 + bias1 + a1;
        const float zo = zx2 + bias2 + a2;
        const float zc = zx3 + bias3 + a3;
        const float fg = sigmoid_fast(zf);
        const float ig = sigmoid_fast(zi);
        const float og = sigmoid_fast(zo);
        const float ct = tanh_fast(zc);
        cst = fg * cst + ig * ct;
        const float hn = og * tanh_fast(cst);
        hlast = hn;

        if (lane == 0) {
            hbuf[(t & 1) * HID + j] = hn;
            Hmat[(size_t)t * HID + j] = hn;
        }
        __syncthreads();                                  // all 8 h-writes of this block done
        if (tid == 0) {
            __threadfence();                              // drain to coherence point (cross-XCD)
            __hip_atomic_store(&flags[b], (unsigned)(t + 1), __ATOMIC_RELEASE,
                               __HIP_MEMORY_SCOPE_AGENT);
        }

        zx0 = nzx0; zx1 = nzx1; zx2 = nzx2; zx3 = nzx3;
    }

    if (lane == 0) { outH[j] = hlast; outC[j] = cst; }
}

// ---------------- out = Hmat @ Wout^T + bout ----------------
// Block: 4 timesteps staged in LDS; wave per channel; lanes split k (coalesced Wout reads).
__global__ __launch_bounds__(256) void out_gemm(const float* __restrict__ H,
                                                const float* __restrict__ Wout,
                                                const float* __restrict__ bout,
                                                float* __restrict__ out) {
    __shared__ float Hs[4][HID];                         // 32 KB
    const int t0 = blockIdx.x * 4;
    const int tid = threadIdx.x;
    {
        const float4* src = (const float4*)(H + (size_t)t0 * HID);
        float4* dst = (float4*)Hs;
        #pragma unroll
        for (int i = tid; i < 4 * HID / 4; i += 256) dst[i] = src[i];
    }
    __syncthreads();
    const int w = tid >> 6, lane = tid & 63;
    for (int ch = w; ch < NCHARS; ch += 4) {
        const float* wrow = Wout + (size_t)ch * HID;
        float acc0 = 0.f, acc1 = 0.f, acc2 = 0.f, acc3 = 0.f;
        #pragma unroll
        for (int q = 0; q < 8; ++q) {
            const int k = q * 256 + lane * 4;
            const float4 wv = *(const float4*)(wrow + k);
            const float4 h0 = *(const float4*)&Hs[0][k];
            const float4 h1 = *(const float4*)&Hs[1][k];
            const float4 h2 = *(const float4*)&Hs[2][k];
            const float4 h3 = *(const float4*)&Hs[3][k];
            acc0 = fmaf(wv.x, h0.x, acc0); acc0 = fmaf(wv.y, h0.y, acc0);
            acc0 = fmaf(wv.z, h0.z, acc0); acc0 = fmaf(wv.w, h0.w, acc0);
            acc1 = fmaf(wv.x, h1.x, acc1); acc1 = fmaf(wv.y, h1.y, acc1);
            acc1 = fmaf(wv.z, h1.z, acc1); acc1 = fmaf(wv.w, h1.w, acc1);
            acc2 = fmaf(wv.x, h2.x, acc2); acc2 = fmaf(wv.y, h2.y, acc2);
            acc2 = fmaf(wv.z, h2.z, acc2); acc2 = fmaf(wv.w, h2.w, acc2);
            acc3 = fmaf(wv.x, h3.x, acc3); acc3 = fmaf(wv.y, h3.y, acc3);
            acc3 = fmaf(wv.z, h3.z, acc3); acc3 = fmaf(wv.w, h3.w, acc3);
        }
        #pragma unroll
        for (int off = 32; off; off >>= 1) {
            acc0 += __shfl_xor(acc0, off, 64);
            acc1 += __shfl_xor(acc1, off, 64);
            acc2 += __shfl_xor(acc2, off, 64);
            acc3 += __shfl_xor(acc3, off, 64);
        }
        if (lane == 0) {
            const float bb = bout[ch];
            out[(size_t)(t0 + 0) * NCHARS + ch] = acc0 + bb;
            out[(size_t)(t0 + 1) * NCHARS + ch] = acc1 + bb;
            out[(size_t)(t0 + 2) * NCHARS + ch] = acc2 + bb;
            out[(size_t)(t0 + 3) * NCHARS + ch] = acc3 + bb;
        }
    }
}

extern "C" void kernel_launch(void* const* d_in, const int* in_sizes, int n_in,
                              void* d_out, int out_size, void* d_ws, size_t ws_size,
                              hipStream_t stream) {
    (void)in_sizes; (void)n_in; (void)out_size; (void)ws_size;
    const int*   seq  = (const int*)  d_in[0];
    const float* emb  = (const float*)d_in[1];
    const float* Wf   = (const float*)d_in[2];
    const float* bfv  = (const float*)d_in[3];
    const float* Wi   = (const float*)d_in[4];
    const float* biv  = (const float*)d_in[5];
    const float* Wo   = (const float*)d_in[6];
    const float* bov  = (const float*)d_in[7];
    const float* Wc   = (const float*)d_in[8];
    const float* bcv  = (const float*)d_in[9];
    const float* Wout = (const float*)d_in[10];
    const float* bout = (const float*)d_in[11];
    float* out = (float*)d_out;

    char* ws = (char*)d_ws;
    size_t off = 0;
    unsigned short* Zx = (unsigned short*)(ws + off);  off += (size_t)SEQLEN * R4 * 2;    // 128 MB
    float* Hm = (float*)(ws + off);                    off += (size_t)SEQLEN * HID * 4;   // 64 MB
    unsigned short* Abf = (unsigned short*)(ws + off); off += (size_t)SEQLEN * EMB * 2;   // 16 MB
    unsigned short* Bbf = (unsigned short*)(ws + off); off += (size_t)R4 * EMB * 2;       // 16 MB
    float* hbuf = (float*)(ws + off);                  off += (size_t)2 * HID * 4;
    unsigned* flags = (unsigned*)(ws + off);           off += 1024;

    hipMemsetAsync(flags, 0, 1024, stream);            // ws is poisoned 0xAA each launch

    prep_a<<<SEQLEN, 256, 0, stream>>>(seq, emb, Abf);
    prep_b<<<R4, 256, 0, stream>>>(Wf, Wi, Wo, Wc, Bbf);

    dim3 gg(R4 / 128, SEQLEN / 128);
    gemm_zx<<<gg, 256, 0, stream>>>(Abf, Bbf, Zx);

    lstm_seq<<<256, 512, 0, stream>>>(Wf, Wi, Wo, Wc, bfv, biv, bov, bcv,
                                      Zx, Hm, hbuf, flags,
                                      out + (size_t)SEQLEN * NCHARS,
                                      out + (size_t)SEQLEN * NCHARS + HID);

    out_gemm<<<SEQLEN / 4, 256, 0, stream>>>(Hm, Wout, bout, out);
}

// Round 5
// 36932.391 us; speedup vs baseline: 8.7037x; 8.7037x over previous
//
#include <hip/hip_runtime.h>

#define SEQLEN 8192
#define EMB    1024
#define HID    2048
#define NCHARS 256
#define DIN    3072   // EMB + HID
#define R4     8192   // 4*HID

typedef __bf16 bf16x8 __attribute__((ext_vector_type(8)));
typedef float  f32x4  __attribute__((ext_vector_type(4)));

__device__ __forceinline__ unsigned short f2bf(float f) {
    unsigned int u = __float_as_uint(f);
    u = (u + 0x7fffu + ((u >> 16) & 1u)) >> 16;   // RNE
    return (unsigned short)u;
}

__device__ __forceinline__ float bf2f(unsigned short u) {
    return __uint_as_float((unsigned)u << 16);
}

__device__ __forceinline__ float sigmoid_fast(float x) {
    return 1.0f / (1.0f + __expf(-x));
}

__device__ __forceinline__ float tanh_fast(float x) {
    float a = fabsf(x);
    float e = __expf(-2.0f * a);
    float r = (1.0f - e) / (1.0f + e);
    return copysignf(r, x);
}

// ---------------- prep: gather emb rows -> bf16 A, W4 input-cols -> bf16 B ----------------
__global__ __launch_bounds__(256) void prep_a(const int* __restrict__ seq,
                                              const float* __restrict__ emb,
                                              unsigned short* __restrict__ A) {
    const int t = blockIdx.x, k4 = threadIdx.x;          // 256 float4 per row == EMB
    const float4 v = ((const float4*)(emb + (size_t)seq[t] * EMB))[k4];
    ushort4 o;
    o.x = f2bf(v.x); o.y = f2bf(v.y); o.z = f2bf(v.z); o.w = f2bf(v.w);
    ((ushort4*)(A + (size_t)t * EMB))[k4] = o;
}

__global__ __launch_bounds__(256) void prep_b(const float* __restrict__ Wf,
                                              const float* __restrict__ Wi,
                                              const float* __restrict__ Wo,
                                              const float* __restrict__ Wc,
                                              unsigned short* __restrict__ B) {
    const int r = blockIdx.x, k4 = threadIdx.x;          // r = g*2048 + j
    const int g = r >> 11, j = r & 2047;
    const float* W = (g == 0) ? Wf : (g == 1) ? Wi : (g == 2) ? Wo : Wc;
    const float4 v = ((const float4*)(W + (size_t)j * DIN))[k4];   // cols [0,1024)
    ushort4 o;
    o.x = f2bf(v.x); o.y = f2bf(v.y); o.z = f2bf(v.z); o.w = f2bf(v.w);
    ((ushort4*)(B + (size_t)r * EMB))[k4] = o;
}

// ---------------- Zx = A(bf16) @ B(bf16)^T  -> bf16 [8192][8192] ----------------
__global__ __launch_bounds__(256) void gemm_zx(const unsigned short* __restrict__ A,
                                               const unsigned short* __restrict__ B,
                                               unsigned short* __restrict__ C) {
    constexpr int K = EMB;
    __shared__ __align__(16) unsigned short As[128 * 32];
    __shared__ __align__(16) unsigned short Bs[128 * 32];
    const int m0 = blockIdx.y * 128, n0 = blockIdx.x * 128;
    const int tid = threadIdx.x, lane = tid & 63;
    const int w = tid >> 6, wr = w >> 1, wc = w & 1;
    f32x4 acc[4][4] = {};
    for (int k0 = 0; k0 < K; k0 += 32) {
        __syncthreads();
        #pragma unroll
        for (int s = 0; s < 2; ++s) {
            const int e = (tid + s * 256) * 8;           // linear bf16 elem in 128x32 tile
            const int row = e >> 5, kk = e & 31;
            *(uint4*)&As[e] = *(const uint4*)&A[(size_t)(m0 + row) * K + k0 + kk];
            *(uint4*)&Bs[e] = *(const uint4*)&B[(size_t)(n0 + row) * K + k0 + kk];
        }
        __syncthreads();
        bf16x8 af[4], bg[4];
        #pragma unroll
        for (int mi = 0; mi < 4; ++mi)
            af[mi] = *(const bf16x8*)&As[(wr * 64 + mi * 16 + (lane & 15)) * 32 + (lane >> 4) * 8];
        #pragma unroll
        for (int ni = 0; ni < 4; ++ni)
            bg[ni] = *(const bf16x8*)&Bs[(wc * 64 + ni * 16 + (lane & 15)) * 32 + (lane >> 4) * 8];
        #pragma unroll
        for (int mi = 0; mi < 4; ++mi)
            #pragma unroll
            for (int ni = 0; ni < 4; ++ni)
                acc[mi][ni] = __builtin_amdgcn_mfma_f32_16x16x32_bf16(af[mi], bg[ni], acc[mi][ni], 0, 0, 0);
    }
    #pragma unroll
    for (int mi = 0; mi < 4; ++mi)
        #pragma unroll
        for (int ni = 0; ni < 4; ++ni)
            #pragma unroll
            for (int r = 0; r < 4; ++r)
                C[(size_t)(m0 + wr * 64 + mi * 16 + (lane >> 4) * 4 + r) * R4
                  + (n0 + wc * 64 + ni * 16 + (lane & 15))] = f2bf(acc[mi][ni][r]);
}

// ---------------- persistent sequential LSTM ----------------
// 256 blocks x 512 threads. Block b owns hidden units j = b*8 + w (wave w = tid>>6).
// h-part weights live in VGPRs. Cross-block h broadcast is SELF-TAGGED 64-bit words:
//   word = ((uint64)(t+1) << 32) | float_bits(h_t[j]),  stored in sync[(t+1)&1][j].
// Producer: ONE relaxed agent-scope atomic store (plain sc1 store to coherence point —
// no wbl2, no release fence: the data travels inside the atomic word, so no ordering
// is needed). Consumer: relaxed agent-scope atomic loads (plain sc1 loads from LLC —
// same freshness as the acquire loads of the previous version, minus the buffer_inv
// L1/L2 invalidate that cost 38.8 us/step). Tag compare is EQUALITY (poison-safe).
// WAR safety (double buffer): writing tag T into slot T&1 overwrites tag T-2; producer
// writes tag T only after reading ALL tag T-1 words; each tag T-1 writer wrote only
// after reading ALL tag T-2 words -> every reader of tag T-2 finished. No race.
// Co-residency: 256 blocks x 8 waves <= 1024 wave-slots -> all resident, no deadlock.
__global__ __launch_bounds__(512, 2) void lstm_seq(
    const float* __restrict__ Wf, const float* __restrict__ Wi,
    const float* __restrict__ Wo, const float* __restrict__ Wc,
    const float* __restrict__ bfv, const float* __restrict__ biv,
    const float* __restrict__ bov, const float* __restrict__ bcv,
    const unsigned short* __restrict__ Zx, float* __restrict__ Hmat,
    unsigned long long* __restrict__ sync,
    float* __restrict__ outH, float* __restrict__ outC)
{
    __shared__ float h_lds[HID];                         // 8 KB
    const int tid = threadIdx.x;
    const int lane = tid & 63;
    const int w = tid >> 6;                              // 0..7
    const int b = blockIdx.x;                            // 0..255
    const int j = b * 8 + w;                             // hidden unit

    // --- load h-part weights into registers (coalesced float4 per lane) ---
    float wreg[4][32];
    {
        const float* Wp[4] = {Wf, Wi, Wo, Wc};
        #pragma unroll
        for (int g = 0; g < 4; ++g) {
            const float* src = Wp[g] + (size_t)j * DIN + EMB;
            #pragma unroll
            for (int q = 0; q < 8; ++q) {
                const float4 v = *(const float4*)(src + q * 256 + lane * 4);
                wreg[g][q * 4 + 0] = v.x; wreg[g][q * 4 + 1] = v.y;
                wreg[g][q * 4 + 2] = v.z; wreg[g][q * 4 + 3] = v.w;
            }
        }
    }
    const float bias0 = bfv[j], bias1 = biv[j], bias2 = bov[j], bias3 = bcv[j];

    float zx0 = bf2f(Zx[(size_t)0 * R4 + 0 * HID + j]);
    float zx1 = bf2f(Zx[(size_t)0 * R4 + 1 * HID + j]);
    float zx2 = bf2f(Zx[(size_t)0 * R4 + 2 * HID + j]);
    float zx3 = bf2f(Zx[(size_t)0 * R4 + 3 * HID + j]);

    float cst = 0.0f, hlast = 0.0f;
    const int segbase = w * 256 + lane * 4;              // this lane's 4 sync words

    for (int t = 0; t < SEQLEN; ++t) {
        // --- stage h_{t-1} segment w (256 floats) into LDS ---
        if (t == 0) {
            *(float4*)&h_lds[segbase] = make_float4(0.f, 0.f, 0.f, 0.f);
        } else {
            const unsigned tag = (unsigned)t;
            const unsigned long long* S = sync + (size_t)(t & 1) * HID;
            unsigned long long w0 = 0, w1 = 0, w2 = 0, w3 = 0;
            bool d0 = false, d1 = false, d2 = false, d3 = false;
            for (;;) {
                if (!d0) { w0 = __hip_atomic_load(&S[segbase + 0], __ATOMIC_RELAXED,
                                                  __HIP_MEMORY_SCOPE_AGENT); d0 = ((unsigned)(w0 >> 32) == tag); }
                if (!d1) { w1 = __hip_atomic_load(&S[segbase + 1], __ATOMIC_RELAXED,
                                                  __HIP_MEMORY_SCOPE_AGENT); d1 = ((unsigned)(w1 >> 32) == tag); }
                if (!d2) { w2 = __hip_atomic_load(&S[segbase + 2], __ATOMIC_RELAXED,
                                                  __HIP_MEMORY_SCOPE_AGENT); d2 = ((unsigned)(w2 >> 32) == tag); }
                if (!d3) { w3 = __hip_atomic_load(&S[segbase + 3], __ATOMIC_RELAXED,
                                                  __HIP_MEMORY_SCOPE_AGENT); d3 = ((unsigned)(w3 >> 32) == tag); }
                if (__all((int)(d0 && d1 && d2 && d3))) break;
            }
            float4 hv;
            hv.x = __uint_as_float((unsigned)w0);
            hv.y = __uint_as_float((unsigned)w1);
            hv.z = __uint_as_float((unsigned)w2);
            hv.w = __uint_as_float((unsigned)w3);
            *(float4*)&h_lds[segbase] = hv;
        }
        __syncthreads();

        // --- matvec: 128 FMAs/lane, 4 independent accumulator chains ---
        float a0 = 0.f, a1 = 0.f, a2 = 0.f, a3 = 0.f;
        #pragma unroll
        for (int q = 0; q < 8; ++q) {
            const float4 hv = *(const float4*)&h_lds[q * 256 + lane * 4];
            a0 = fmaf(wreg[0][q * 4 + 0], hv.x, a0); a1 = fmaf(wreg[1][q * 4 + 0], hv.x, a1);
            a2 = fmaf(wreg[2][q * 4 + 0], hv.x, a2); a3 = fmaf(wreg[3][q * 4 + 0], hv.x, a3);
            a0 = fmaf(wreg[0][q * 4 + 1], hv.y, a0); a1 = fmaf(wreg[1][q * 4 + 1], hv.y, a1);
            a2 = fmaf(wreg[2][q * 4 + 1], hv.y, a2); a3 = fmaf(wreg[3][q * 4 + 1], hv.y, a3);
            a0 = fmaf(wreg[0][q * 4 + 2], hv.z, a0); a1 = fmaf(wreg[1][q * 4 + 2], hv.z, a1);
            a2 = fmaf(wreg[2][q * 4 + 2], hv.z, a2); a3 = fmaf(wreg[3][q * 4 + 2], hv.z, a3);
            a0 = fmaf(wreg[0][q * 4 + 3], hv.w, a0); a1 = fmaf(wreg[1][q * 4 + 3], hv.w, a1);
            a2 = fmaf(wreg[2][q * 4 + 3], hv.w, a2); a3 = fmaf(wreg[3][q * 4 + 3], hv.w, a3);
        }

        // --- prefetch next step's Zx (broadcast load, hidden under reduce/gates) ---
        float nzx0 = 0.f, nzx1 = 0.f, nzx2 = 0.f, nzx3 = 0.f;
        if (t + 1 < SEQLEN) {
            const size_t base = (size_t)(t + 1) * R4 + j;
            nzx0 = bf2f(Zx[base]);           nzx1 = bf2f(Zx[base + HID]);
            nzx2 = bf2f(Zx[base + 2 * HID]); nzx3 = bf2f(Zx[base + 3 * HID]);
        }

        // --- reduce across the 64 lanes ---
        #pragma unroll
        for (int off = 32; off; off >>= 1) {
            a0 += __shfl_xor(a0, off, 64);
            a1 += __shfl_xor(a1, off, 64);
            a2 += __shfl_xor(a2, off, 64);
            a3 += __shfl_xor(a3, off, 64);
        }

        // --- gates (all lanes redundantly; lane0 stores) ---
        const float zf = zx0 + bias0 + a0;
        const float zi = zx1 + bias1 + a1;
        const float zo = zx2 + bias2 + a2;
        const float zc = zx3 + bias3 + a3;
        const float fg = sigmoid_fast(zf);
        const float ig = sigmoid_fast(zi);
        const float og = sigmoid_fast(zo);
        const float ct = tanh_fast(zc);
        cst = fg * cst + ig * ct;
        const float hn = og * tanh_fast(cst);
        hlast = hn;

        if (lane == 0) {
            // critical-path publish FIRST: self-tagged word, relaxed, agent scope
            const unsigned long long pw =
                ((unsigned long long)(unsigned)(t + 1) << 32) | (unsigned)__float_as_uint(hn);
            __hip_atomic_store(&sync[(size_t)((t + 1) & 1) * HID + j], pw,
                               __ATOMIC_RELAXED, __HIP_MEMORY_SCOPE_AGENT);
            Hmat[(size_t)t * HID + j] = hn;
        }
        __syncthreads();                                  // h_lds reads done before next staging

        zx0 = nzx0; zx1 = nzx1; zx2 = nzx2; zx3 = nzx3;
    }

    if (lane == 0) { outH[j] = hlast; outC[j] = cst; }
}

// ---------------- out = Hmat @ Wout^T + bout ----------------
__global__ __launch_bounds__(256) void out_gemm(const float* __restrict__ H,
                                                const float* __restrict__ Wout,
                                                const float* __restrict__ bout,
                                                float* __restrict__ out) {
    __shared__ float Hs[4][HID];                         // 32 KB
    const int t0 = blockIdx.x * 4;
    const int tid = threadIdx.x;
    {
        const float4* src = (const float4*)(H + (size_t)t0 * HID);
        float4* dst = (float4*)Hs;
        #pragma unroll
        for (int i = tid; i < 4 * HID / 4; i += 256) dst[i] = src[i];
    }
    __syncthreads();
    const int w = tid >> 6, lane = tid & 63;
    for (int ch = w; ch < NCHARS; ch += 4) {
        const float* wrow = Wout + (size_t)ch * HID;
        float acc0 = 0.f, acc1 = 0.f, acc2 = 0.f, acc3 = 0.f;
        #pragma unroll
        for (int q = 0; q < 8; ++q) {
            const int k = q * 256 + lane * 4;
            const float4 wv = *(const float4*)(wrow + k);
            const float4 h0 = *(const float4*)&Hs[0][k];
            const float4 h1 = *(const float4*)&Hs[1][k];
            const float4 h2 = *(const float4*)&Hs[2][k];
            const float4 h3 = *(const float4*)&Hs[3][k];
            acc0 = fmaf(wv.x, h0.x, acc0); acc0 = fmaf(wv.y, h0.y, acc0);
            acc0 = fmaf(wv.z, h0.z, acc0); acc0 = fmaf(wv.w, h0.w, acc0);
            acc1 = fmaf(wv.x, h1.x, acc1); acc1 = fmaf(wv.y, h1.y, acc1);
            acc1 = fmaf(wv.z, h1.z, acc1); acc1 = fmaf(wv.w, h1.w, acc1);
            acc2 = fmaf(wv.x, h2.x, acc2); acc2 = fmaf(wv.y, h2.y, acc2);
            acc2 = fmaf(wv.z, h2.z, acc2); acc2 = fmaf(wv.w, h2.w, acc2);
            acc3 = fmaf(wv.x, h3.x, acc3); acc3 = fmaf(wv.y, h3.y, acc3);
            acc3 = fmaf(wv.z, h3.z, acc3); acc3 = fmaf(wv.w, h3.w, acc3);
        }
        #pragma unroll
        for (int off = 32; off; off >>= 1) {
            acc0 += __shfl_xor(acc0, off, 64);
            acc1 += __shfl_xor(acc1, off, 64);
            acc2 += __shfl_xor(acc2, off, 64);
            acc3 += __shfl_xor(acc3, off, 64);
        }
        if (lane == 0) {
            const float bb = bout[ch];
            out[(size_t)(t0 + 0) * NCHARS + ch] = acc0 + bb;
            out[(size_t)(t0 + 1) * NCHARS + ch] = acc1 + bb;
            out[(size_t)(t0 + 2) * NCHARS + ch] = acc2 + bb;
            out[(size_t)(t0 + 3) * NCHARS + ch] = acc3 + bb;
        }
    }
}

extern "C" void kernel_launch(void* const* d_in, const int* in_sizes, int n_in,
                              void* d_out, int out_size, void* d_ws, size_t ws_size,
                              hipStream_t stream) {
    (void)in_sizes; (void)n_in; (void)out_size; (void)ws_size;
    const int*   seq  = (const int*)  d_in[0];
    const float* emb  = (const float*)d_in[1];
    const float* Wf   = (const float*)d_in[2];
    const float* bfv  = (const float*)d_in[3];
    const float* Wi   = (const float*)d_in[4];
    const float* biv  = (const float*)d_in[5];
    const float* Wo   = (const float*)d_in[6];
    const float* bov  = (const float*)d_in[7];
    const float* Wc   = (const float*)d_in[8];
    const float* bcv  = (const float*)d_in[9];
    const float* Wout = (const float*)d_in[10];
    const float* bout = (const float*)d_in[11];
    float* out = (float*)d_out;

    char* ws = (char*)d_ws;
    size_t off = 0;
    unsigned short* Zx = (unsigned short*)(ws + off);  off += (size_t)SEQLEN * R4 * 2;    // 128 MB
    float* Hm = (float*)(ws + off);                    off += (size_t)SEQLEN * HID * 4;   // 64 MB
    unsigned short* Abf = (unsigned short*)(ws + off); off += (size_t)SEQLEN * EMB * 2;   // 16 MB
    unsigned short* Bbf = (unsigned short*)(ws + off); off += (size_t)R4 * EMB * 2;       // 16 MB
    unsigned long long* sync = (unsigned long long*)(ws + off); off += (size_t)2 * HID * 8; // 32 KB
    // no memset needed: tag compare is EQUALITY, 0xAA poison never matches tags 1..8192

    prep_a<<<SEQLEN, 256, 0, stream>>>(seq, emb, Abf);
    prep_b<<<R4, 256, 0, stream>>>(Wf, Wi, Wo, Wc, Bbf);

    dim3 gg(R4 / 128, SEQLEN / 128);
    gemm_zx<<<gg, 256, 0, stream>>>(Abf, Bbf, Zx);

    lstm_seq<<<256, 512, 0, stream>>>(Wf, Wi, Wo, Wc, bfv, biv, bov, bcv,
                                      Zx, Hm, sync,
                                      out + (size_t)SEQLEN * NCHARS,
                                      out + (size_t)SEQLEN * NCHARS + HID);

    out_gemm<<<SEQLEN / 4, 256, 0, stream>>>(Hm, Wout, bout, out);
}

// Round 6
// 20182.317 us; speedup vs baseline: 15.9272x; 1.8299x over previous
//
#include <hip/hip_runtime.h>

#define SEQLEN 8192
#define EMB    1024
#define HID    2048
#define NCHARS 256
#define DIN    3072   // EMB + HID
#define R4     8192   // 4*HID

typedef __bf16 bf16x8 __attribute__((ext_vector_type(8)));
typedef float  f32x4  __attribute__((ext_vector_type(4)));
typedef unsigned u32x4 __attribute__((ext_vector_type(4)));

__device__ __forceinline__ unsigned short f2bf(float f) {
    unsigned int u = __float_as_uint(f);
    u = (u + 0x7fffu + ((u >> 16) & 1u)) >> 16;   // RNE
    return (unsigned short)u;
}

__device__ __forceinline__ float bf2f(unsigned short u) {
    return __uint_as_float((unsigned)u << 16);
}

__device__ __forceinline__ float sigmoid_fast(float x) {
    return 1.0f / (1.0f + __expf(-x));
}

__device__ __forceinline__ float tanh_fast(float x) {
    float a = fabsf(x);
    float e = __expf(-2.0f * a);
    float r = (1.0f - e) / (1.0f + e);
    return copysignf(r, x);
}

// LLC-coherent 16B load (bypass L1+local L2; per-dword atomicity of an aligned
// dwordx4 is guaranteed — each dword comes whole from one cache-line read).
__device__ __forceinline__ u32x4 llc_load4(const unsigned* p) {
    u32x4 r;
    asm volatile("global_load_dwordx4 %0, %1, off sc0 sc1\n\ts_waitcnt vmcnt(0)"
                 : "=v"(r) : "v"(p) : "memory");
    return r;
}

// LLC write-through publish store.
__device__ __forceinline__ void llc_store(unsigned* p, unsigned v) {
    asm volatile("global_store_dword %0, %1, off sc0 sc1" :: "v"(p), "v"(v) : "memory");
}

// ---------------- prep: gather emb rows -> bf16 A, W4 input-cols -> bf16 B ----------------
__global__ __launch_bounds__(256) void prep_a(const int* __restrict__ seq,
                                              const float* __restrict__ emb,
                                              unsigned short* __restrict__ A) {
    const int t = blockIdx.x, k4 = threadIdx.x;          // 256 float4 per row == EMB
    const float4 v = ((const float4*)(emb + (size_t)seq[t] * EMB))[k4];
    ushort4 o;
    o.x = f2bf(v.x); o.y = f2bf(v.y); o.z = f2bf(v.z); o.w = f2bf(v.w);
    ((ushort4*)(A + (size_t)t * EMB))[k4] = o;
}

__global__ __launch_bounds__(256) void prep_b(const float* __restrict__ Wf,
                                              const float* __restrict__ Wi,
                                              const float* __restrict__ Wo,
                                              const float* __restrict__ Wc,
                                              unsigned short* __restrict__ B) {
    const int r = blockIdx.x, k4 = threadIdx.x;          // r = g*2048 + j
    const int g = r >> 11, j = r & 2047;
    const float* W = (g == 0) ? Wf : (g == 1) ? Wi : (g == 2) ? Wo : Wc;
    const float4 v = ((const float4*)(W + (size_t)j * DIN))[k4];   // cols [0,1024)
    ushort4 o;
    o.x = f2bf(v.x); o.y = f2bf(v.y); o.z = f2bf(v.z); o.w = f2bf(v.w);
    ((ushort4*)(B + (size_t)r * EMB))[k4] = o;
}

// ---------------- Zx = A(bf16) @ B(bf16)^T  -> bf16 [8192][8192] ----------------
__global__ __launch_bounds__(256) void gemm_zx(const unsigned short* __restrict__ A,
                                               const unsigned short* __restrict__ B,
                                               unsigned short* __restrict__ C) {
    constexpr int K = EMB;
    __shared__ __align__(16) unsigned short As[128 * 32];
    __shared__ __align__(16) unsigned short Bs[128 * 32];
    const int m0 = blockIdx.y * 128, n0 = blockIdx.x * 128;
    const int tid = threadIdx.x, lane = tid & 63;
    const int w = tid >> 6, wr = w >> 1, wc = w & 1;
    f32x4 acc[4][4] = {};
    for (int k0 = 0; k0 < K; k0 += 32) {
        __syncthreads();
        #pragma unroll
        for (int s = 0; s < 2; ++s) {
            const int e = (tid + s * 256) * 8;           // linear bf16 elem in 128x32 tile
            const int row = e >> 5, kk = e & 31;
            *(uint4*)&As[e] = *(const uint4*)&A[(size_t)(m0 + row) * K + k0 + kk];
            *(uint4*)&Bs[e] = *(const uint4*)&B[(size_t)(n0 + row) * K + k0 + kk];
        }
        __syncthreads();
        bf16x8 af[4], bg[4];
        #pragma unroll
        for (int mi = 0; mi < 4; ++mi)
            af[mi] = *(const bf16x8*)&As[(wr * 64 + mi * 16 + (lane & 15)) * 32 + (lane >> 4) * 8];
        #pragma unroll
        for (int ni = 0; ni < 4; ++ni)
            bg[ni] = *(const bf16x8*)&Bs[(wc * 64 + ni * 16 + (lane & 15)) * 32 + (lane >> 4) * 8];
        #pragma unroll
        for (int mi = 0; mi < 4; ++mi)
            #pragma unroll
            for (int ni = 0; ni < 4; ++ni)
                acc[mi][ni] = __builtin_amdgcn_mfma_f32_16x16x32_bf16(af[mi], bg[ni], acc[mi][ni], 0, 0, 0);
    }
    #pragma unroll
    for (int mi = 0; mi < 4; ++mi)
        #pragma unroll
        for (int ni = 0; ni < 4; ++ni)
            #pragma unroll
            for (int r = 0; r < 4; ++r)
                C[(size_t)(m0 + wr * 64 + mi * 16 + (lane >> 4) * 4 + r) * R4
                  + (n0 + wc * 64 + ni * 16 + (lane & 15))] = f2bf(acc[mi][ni][r]);
}

// ---------------- persistent sequential LSTM ----------------
// 256 blocks x 512 threads. Block b owns units j = b*8 + w (wave w = tid>>6).
// Sync words are 32-bit SELF-TAGGED: word = (h_bits & ~0xF) | ((t+1)&0xF), in
// slot (t+1)&1. Tag-in-mantissa costs 2^-19 rel error on h (negligible).
//   - poison 0xAAAAAAAA nibble = 0xA != first tags {1,2} -> poison-safe.
//   - mod-16 tag aliasing impossible: a reader's previous observation of a slot
//     was tag t-2; per-address coherence -> next read returns t-2 or t, never
//     anything older; t-2 != t (mod 16).
// Publish AFTER bar#2 -> its LLC ack drains during the NEXT step's poll.
// Zx prefetch ISSUED at top of step (before poll) -> first poll iteration's
// vmcnt(0) absorbs its HBM latency instead of the barrier.
// Weights PINNED in VGPRs via asm "+v" on all 32 f32x4 (defs become opaque ->
// no rematerialized per-step reloads; r5 showed VGPR_Count=100 => spill-reload).
__global__ __launch_bounds__(512, 2) void lstm_seq(
    const float* __restrict__ Wf, const float* __restrict__ Wi,
    const float* __restrict__ Wo, const float* __restrict__ Wc,
    const float* __restrict__ bfv, const float* __restrict__ biv,
    const float* __restrict__ bov, const float* __restrict__ bcv,
    const unsigned short* __restrict__ Zx, float* __restrict__ Hmat,
    unsigned* __restrict__ sync,
    float* __restrict__ outH, float* __restrict__ outC)
{
    __shared__ __align__(16) float h_lds[HID];           // 8 KB
    const int tid = threadIdx.x;
    const int lane = tid & 63;
    const int w = tid >> 6;                              // 0..7
    const int b = blockIdx.x;                            // 0..255
    const int j = b * 8 + w;                             // hidden unit

    // --- load h-part weights into registers and PIN them ---
    f32x4 wv[32];                                        // [g*8+q]
    {
        const float* Wp[4] = {Wf, Wi, Wo, Wc};
        #pragma unroll
        for (int g = 0; g < 4; ++g) {
            const float* src = Wp[g] + (size_t)j * DIN + EMB;
            #pragma unroll
            for (int q = 0; q < 8; ++q)
                wv[g * 8 + q] = *(const f32x4*)(src + q * 256 + lane * 4);
        }
    }
    asm volatile("" :
        "+v"(wv[0]), "+v"(wv[1]), "+v"(wv[2]), "+v"(wv[3]),
        "+v"(wv[4]), "+v"(wv[5]), "+v"(wv[6]), "+v"(wv[7]),
        "+v"(wv[8]), "+v"(wv[9]), "+v"(wv[10]), "+v"(wv[11]),
        "+v"(wv[12]), "+v"(wv[13]), "+v"(wv[14]), "+v"(wv[15]),
        "+v"(wv[16]), "+v"(wv[17]), "+v"(wv[18]), "+v"(wv[19]),
        "+v"(wv[20]), "+v"(wv[21]), "+v"(wv[22]), "+v"(wv[23]),
        "+v"(wv[24]), "+v"(wv[25]), "+v"(wv[26]), "+v"(wv[27]),
        "+v"(wv[28]), "+v"(wv[29]), "+v"(wv[30]), "+v"(wv[31]));

    const float bias0 = bfv[j], bias1 = biv[j], bias2 = bov[j], bias3 = bcv[j];

    float zx0 = bf2f(Zx[(size_t)0 * R4 + 0 * HID + j]);
    float zx1 = bf2f(Zx[(size_t)0 * R4 + 1 * HID + j]);
    float zx2 = bf2f(Zx[(size_t)0 * R4 + 2 * HID + j]);
    float zx3 = bf2f(Zx[(size_t)0 * R4 + 3 * HID + j]);

    float cst = 0.0f, hlast = 0.0f;
    const int segbase = w * 256 + lane * 4;              // this lane's 4 unit slots

    for (int t = 0; t < SEQLEN; ++t) {
        // --- issue next step's Zx loads FIRST (drained inside the poll) ---
        float nzx0 = 0.f, nzx1 = 0.f, nzx2 = 0.f, nzx3 = 0.f;
        if (t + 1 < SEQLEN) {
            const size_t base = (size_t)(t + 1) * R4 + j;
            nzx0 = bf2f(Zx[base]);           nzx1 = bf2f(Zx[base + HID]);
            nzx2 = bf2f(Zx[base + 2 * HID]); nzx3 = bf2f(Zx[base + 3 * HID]);
        }

        // --- poll + stage h_{t-1} segment (256 floats per wave) into LDS ---
        if (t == 0) {
            *(f32x4*)&h_lds[segbase] = (f32x4){0.f, 0.f, 0.f, 0.f};
        } else {
            const unsigned tag = (unsigned)(t & 15);
            const unsigned* S = sync + (size_t)(t & 1) * HID + segbase;
            u32x4 v;
            for (;;) {
                v = llc_load4(S);
                const bool ok = ((v[0] & 15u) == tag) & ((v[1] & 15u) == tag) &
                                ((v[2] & 15u) == tag) & ((v[3] & 15u) == tag);
                if (__all((int)ok)) break;
            }
            f32x4 hv;
            hv[0] = __uint_as_float(v[0]); hv[1] = __uint_as_float(v[1]);
            hv[2] = __uint_as_float(v[2]); hv[3] = __uint_as_float(v[3]);
            *(f32x4*)&h_lds[segbase] = hv;
        }
        __syncthreads();                                  // bar#1

        // --- matvec: 128 FMAs/lane, 4 independent accumulator chains ---
        float a0 = 0.f, a1 = 0.f, a2 = 0.f, a3 = 0.f;
        #pragma unroll
        for (int q = 0; q < 8; ++q) {
            const f32x4 hv = *(const f32x4*)&h_lds[q * 256 + lane * 4];
            #pragma unroll
            for (int u = 0; u < 4; ++u) {
                a0 = fmaf(wv[0 * 8 + q][u], hv[u], a0);
                a1 = fmaf(wv[1 * 8 + q][u], hv[u], a1);
                a2 = fmaf(wv[2 * 8 + q][u], hv[u], a2);
                a3 = fmaf(wv[3 * 8 + q][u], hv[u], a3);
            }
        }

        // --- reduce across the 64 lanes ---
        #pragma unroll
        for (int off = 32; off; off >>= 1) {
            a0 += __shfl_xor(a0, off, 64);
            a1 += __shfl_xor(a1, off, 64);
            a2 += __shfl_xor(a2, off, 64);
            a3 += __shfl_xor(a3, off, 64);
        }

        // --- gates (all lanes redundantly; lane0 publishes) ---
        const float zf = zx0 + bias0 + a0;
        const float zi = zx1 + bias1 + a1;
        const float zo = zx2 + bias2 + a2;
        const float zc = zx3 + bias3 + a3;
        const float fg = sigmoid_fast(zf);
        const float ig = sigmoid_fast(zi);
        const float og = sigmoid_fast(zo);
        const float ct = tanh_fast(zc);
        cst = fg * cst + ig * ct;
        const float hn = og * tanh_fast(cst);
        hlast = hn;

        __syncthreads();                                  // bar#2: all h_lds reads done
        if (lane == 0) {
            const unsigned pw = (__float_as_uint(hn) & ~15u) | ((unsigned)(t + 1) & 15u);
            llc_store(&sync[(size_t)((t + 1) & 1) * HID + j], pw);
            Hmat[(size_t)t * HID + j] = hn;               // acks drain in next poll
        }

        zx0 = nzx0; zx1 = nzx1; zx2 = nzx2; zx3 = nzx3;
    }

    if (lane == 0) { outH[j] = hlast; outC[j] = cst; }
}

// ---------------- out = Hmat @ Wout^T + bout ----------------
__global__ __launch_bounds__(256) void out_gemm(const float* __restrict__ H,
                                                const float* __restrict__ Wout,
                                                const float* __restrict__ bout,
                                                float* __restrict__ out) {
    __shared__ float Hs[4][HID];                         // 32 KB
    const int t0 = blockIdx.x * 4;
    const int tid = threadIdx.x;
    {
        const float4* src = (const float4*)(H + (size_t)t0 * HID);
        float4* dst = (float4*)Hs;
        #pragma unroll
        for (int i = tid; i < 4 * HID / 4; i += 256) dst[i] = src[i];
    }
    __syncthreads();
    const int w = tid >> 6, lane = tid & 63;
    for (int ch = w; ch < NCHARS; ch += 4) {
        const float* wrow = Wout + (size_t)ch * HID;
        float acc0 = 0.f, acc1 = 0.f, acc2 = 0.f, acc3 = 0.f;
        #pragma unroll
        for (int q = 0; q < 8; ++q) {
            const int k = q * 256 + lane * 4;
            const float4 wvv = *(const float4*)(wrow + k);
            const float4 h0 = *(const float4*)&Hs[0][k];
            const float4 h1 = *(const float4*)&Hs[1][k];
            const float4 h2 = *(const float4*)&Hs[2][k];
            const float4 h3 = *(const float4*)&Hs[3][k];
            acc0 = fmaf(wvv.x, h0.x, acc0); acc0 = fmaf(wvv.y, h0.y, acc0);
            acc0 = fmaf(wvv.z, h0.z, acc0); acc0 = fmaf(wvv.w, h0.w, acc0);
            acc1 = fmaf(wvv.x, h1.x, acc1); acc1 = fmaf(wvv.y, h1.y, acc1);
            acc1 = fmaf(wvv.z, h1.z, acc1); acc1 = fmaf(wvv.w, h1.w, acc1);
            acc2 = fmaf(wvv.x, h2.x, acc2); acc2 = fmaf(wvv.y, h2.y, acc2);
            acc2 = fmaf(wvv.z, h2.z, acc2); acc2 = fmaf(wvv.w, h2.w, acc2);
            acc3 = fmaf(wvv.x, h3.x, acc3); acc3 = fmaf(wvv.y, h3.y, acc3);
            acc3 = fmaf(wvv.z, h3.z, acc3); acc3 = fmaf(wvv.w, h3.w, acc3);
        }
        #pragma unroll
        for (int off = 32; off; off >>= 1) {
            acc0 += __shfl_xor(acc0, off, 64);
            acc1 += __shfl_xor(acc1, off, 64);
            acc2 += __shfl_xor(acc2, off, 64);
            acc3 += __shfl_xor(acc3, off, 64);
        }
        if (lane == 0) {
            const float bb = bout[ch];
            out[(size_t)(t0 + 0) * NCHARS + ch] = acc0 + bb;
            out[(size_t)(t0 + 1) * NCHARS + ch] = acc1 + bb;
            out[(size_t)(t0 + 2) * NCHARS + ch] = acc2 + bb;
            out[(size_t)(t0 + 3) * NCHARS + ch] = acc3 + bb;
        }
    }
}

extern "C" void kernel_launch(void* const* d_in, const int* in_sizes, int n_in,
                              void* d_out, int out_size, void* d_ws, size_t ws_size,
                              hipStream_t stream) {
    (void)in_sizes; (void)n_in; (void)out_size; (void)ws_size;
    const int*   seq  = (const int*)  d_in[0];
    const float* emb  = (const float*)d_in[1];
    const float* Wf   = (const float*)d_in[2];
    const float* bfv  = (const float*)d_in[3];
    const float* Wi   = (const float*)d_in[4];
    const float* biv  = (const float*)d_in[5];
    const float* Wo   = (const float*)d_in[6];
    const float* bov  = (const float*)d_in[7];
    const float* Wc   = (const float*)d_in[8];
    const float* bcv  = (const float*)d_in[9];
    const float* Wout = (const float*)d_in[10];
    const float* bout = (const float*)d_in[11];
    float* out = (float*)d_out;

    char* ws = (char*)d_ws;
    size_t off = 0;
    unsigned short* Zx = (unsigned short*)(ws + off);  off += (size_t)SEQLEN * R4 * 2;    // 128 MB
    float* Hm = (float*)(ws + off);                    off += (size_t)SEQLEN * HID * 4;   // 64 MB
    unsigned short* Abf = (unsigned short*)(ws + off); off += (size_t)SEQLEN * EMB * 2;   // 16 MB
    unsigned short* Bbf = (unsigned short*)(ws + off); off += (size_t)R4 * EMB * 2;       // 16 MB
    unsigned* sync = (unsigned*)(ws + off);            off += (size_t)2 * HID * 4;        // 16 KB
    // no memset needed: tag nibble of 0xAA poison (0xA) never matches first tags {1,2}

    prep_a<<<SEQLEN, 256, 0, stream>>>(seq, emb, Abf);
    prep_b<<<R4, 256, 0, stream>>>(Wf, Wi, Wo, Wc, Bbf);

    dim3 gg(R4 / 128, SEQLEN / 128);
    gemm_zx<<<gg, 256, 0, stream>>>(Abf, Bbf, Zx);

    lstm_seq<<<256, 512, 0, stream>>>(Wf, Wi, Wo, Wc, bfv, biv, bov, bcv,
                                      Zx, Hm, sync,
                                      out + (size_t)SEQLEN * NCHARS,
                                      out + (size_t)SEQLEN * NCHARS + HID);

    out_gemm<<<SEQLEN / 4, 256, 0, stream>>>(Hm, Wout, bout, out);
}

// Round 9
// 20104.080 us; speedup vs baseline: 15.9892x; 1.0039x over previous
//
#include <hip/hip_runtime.h>

#define SEQLEN 8192
#define EMB    1024
#define HID    2048
#define NCHARS 256
#define DIN    3072   // EMB + HID
#define R4     8192   // 4*HID

typedef __bf16 bf16x8 __attribute__((ext_vector_type(8)));
typedef float  f32x4  __attribute__((ext_vector_type(4)));
typedef unsigned u32x4 __attribute__((ext_vector_type(4)));

__device__ __forceinline__ unsigned short f2bf(float f) {
    unsigned int u = __float_as_uint(f);
    u = (u + 0x7fffu + ((u >> 16) & 1u)) >> 16;   // RNE
    return (unsigned short)u;
}

__device__ __forceinline__ float bf2f(unsigned short u) {
    return __uint_as_float((unsigned)u << 16);
}

__device__ __forceinline__ float sigmoid_fast(float x) {
    return 1.0f / (1.0f + __expf(-x));
}

__device__ __forceinline__ float tanh_fast(float x) {
    float a = fabsf(x);
    float e = __expf(-2.0f * a);
    float r = (1.0f - e) / (1.0f + e);
    return copysignf(r, x);
}

// LLC-coherent 16B load (bypass L1+local L2; per-dword atomicity of an aligned
// dwordx4 is guaranteed — each dword comes whole from one cache-line read).
__device__ __forceinline__ u32x4 llc_load4(const unsigned* p) {
    u32x4 r;
    asm volatile("global_load_dwordx4 %0, %1, off sc0 sc1\n\ts_waitcnt vmcnt(0)"
                 : "=v"(r) : "v"(p) : "memory");
    return r;
}

// LLC write-through publish store.
__device__ __forceinline__ void llc_store(unsigned* p, unsigned v) {
    asm volatile("global_store_dword %0, %1, off sc0 sc1" :: "v"(p), "v"(v) : "memory");
}

#define PIN_WEIGHTS(wv) asm volatile("" :                               \
        "+v"(wv[0]), "+v"(wv[1]), "+v"(wv[2]), "+v"(wv[3]),             \
        "+v"(wv[4]), "+v"(wv[5]), "+v"(wv[6]), "+v"(wv[7]),             \
        "+v"(wv[8]), "+v"(wv[9]), "+v"(wv[10]), "+v"(wv[11]),           \
        "+v"(wv[12]), "+v"(wv[13]), "+v"(wv[14]), "+v"(wv[15]),         \
        "+v"(wv[16]), "+v"(wv[17]), "+v"(wv[18]), "+v"(wv[19]),         \
        "+v"(wv[20]), "+v"(wv[21]), "+v"(wv[22]), "+v"(wv[23]),         \
        "+v"(wv[24]), "+v"(wv[25]), "+v"(wv[26]), "+v"(wv[27]),         \
        "+v"(wv[28]), "+v"(wv[29]), "+v"(wv[30]), "+v"(wv[31]))

// ---------------- prep: gather emb rows -> bf16 A, W4 input-cols -> bf16 B ----------------
__global__ __launch_bounds__(256) void prep_a(const int* __restrict__ seq,
                                              const float* __restrict__ emb,
                                              unsigned short* __restrict__ A) {
    const int t = blockIdx.x, k4 = threadIdx.x;          // 256 float4 per row == EMB
    const float4 v = ((const float4*)(emb + (size_t)seq[t] * EMB))[k4];
    ushort4 o;
    o.x = f2bf(v.x); o.y = f2bf(v.y); o.z = f2bf(v.z); o.w = f2bf(v.w);
    ((ushort4*)(A + (size_t)t * EMB))[k4] = o;
}

__global__ __launch_bounds__(256) void prep_b(const float* __restrict__ Wf,
                                              const float* __restrict__ Wi,
                                              const float* __restrict__ Wo,
                                              const float* __restrict__ Wc,
                                              unsigned short* __restrict__ B) {
    const int r = blockIdx.x, k4 = threadIdx.x;          // r = g*2048 + j
    const int g = r >> 11, j = r & 2047;
    const float* W = (g == 0) ? Wf : (g == 1) ? Wi : (g == 2) ? Wo : Wc;
    const float4 v = ((const float4*)(W + (size_t)j * DIN))[k4];   // cols [0,1024)
    ushort4 o;
    o.x = f2bf(v.x); o.y = f2bf(v.y); o.z = f2bf(v.z); o.w = f2bf(v.w);
    ((ushort4*)(B + (size_t)r * EMB))[k4] = o;
}

// ---------------- Zx = A(bf16) @ B(bf16)^T  -> bf16 [8192][8192] ----------------
__global__ __launch_bounds__(256) void gemm_zx(const unsigned short* __restrict__ A,
                                               const unsigned short* __restrict__ B,
                                               unsigned short* __restrict__ C) {
    constexpr int K = EMB;
    __shared__ __align__(16) unsigned short As[128 * 32];
    __shared__ __align__(16) unsigned short Bs[128 * 32];
    const int m0 = blockIdx.y * 128, n0 = blockIdx.x * 128;
    const int tid = threadIdx.x, lane = tid & 63;
    const int w = tid >> 6, wr = w >> 1, wc = w & 1;
    f32x4 acc[4][4] = {};
    for (int k0 = 0; k0 < K; k0 += 32) {
        __syncthreads();
        #pragma unroll
        for (int s = 0; s < 2; ++s) {
            const int e = (tid + s * 256) * 8;           // linear bf16 elem in 128x32 tile
            const int row = e >> 5, kk = e & 31;
            *(uint4*)&As[e] = *(const uint4*)&A[(size_t)(m0 + row) * K + k0 + kk];
            *(uint4*)&Bs[e] = *(const uint4*)&B[(size_t)(n0 + row) * K + k0 + kk];
        }
        __syncthreads();
        bf16x8 af[4], bg[4];
        #pragma unroll
        for (int mi = 0; mi < 4; ++mi)
            af[mi] = *(const bf16x8*)&As[(wr * 64 + mi * 16 + (lane & 15)) * 32 + (lane >> 4) * 8];
        #pragma unroll
        for (int ni = 0; ni < 4; ++ni)
            bg[ni] = *(const bf16x8*)&Bs[(wc * 64 + ni * 16 + (lane & 15)) * 32 + (lane >> 4) * 8];
        #pragma unroll
        for (int mi = 0; mi < 4; ++mi)
            #pragma unroll
            for (int ni = 0; ni < 4; ++ni)
                acc[mi][ni] = __builtin_amdgcn_mfma_f32_16x16x32_bf16(af[mi], bg[ni], acc[mi][ni], 0, 0, 0);
    }
    #pragma unroll
    for (int mi = 0; mi < 4; ++mi)
        #pragma unroll
        for (int ni = 0; ni < 4; ++ni)
            #pragma unroll
            for (int r = 0; r < 4; ++r)
                C[(size_t)(m0 + wr * 64 + mi * 16 + (lane >> 4) * 4 + r) * R4
                  + (n0 + wc * 64 + ni * 16 + (lane & 15))] = f2bf(acc[mi][ni][r]);
}

// ---------------- persistent sequential LSTM ----------------
// 256 blocks x 512 threads. Block b owns units j = b*8 + w (wave w = tid>>6).
// Sync words are 32-bit SELF-TAGGED: word = (h_bits & ~0xF) | ((t+1)&0xF), in
// slot (t+1)&1 (tag-in-mantissa: 2^-19 rel err; poison nibble 0xA != tags 1,2;
// mod-16 aliasing impossible via per-address coherence — see r5 notes).
// Publish AFTER bar#2; Zx prefetch issued before the poll (its vmcnt(0) absorbs
// the HBM latency).
// WEIGHT RESIDENCY: r6 showed VGPR_Count=84 — a single init-time asm pin does
// NOT keep the 128 weight floats resident; the allocator spilled and re-loaded
// ~256KB/block/step from L2 (the ~1us/step matvec tax + L2 thrash at 8MB/XCD).
// Fix: the empty "+v" pin asm is INSIDE the t-loop -> loop-carried constraint,
// all 32 f32x4 must be in VGPRs at every iteration top -> allocator keeps them
// resident. Success signature: VGPR_Count >= ~170.
__global__ __launch_bounds__(512, 2) void lstm_seq(
    const float* __restrict__ Wf, const float* __restrict__ Wi,
    const float* __restrict__ Wo, const float* __restrict__ Wc,
    const float* __restrict__ bfv, const float* __restrict__ biv,
    const float* __restrict__ bov, const float* __restrict__ bcv,
    const unsigned short* __restrict__ Zx, float* __restrict__ Hmat,
    unsigned* __restrict__ sync,
    float* __restrict__ outH, float* __restrict__ outC)
{
    __shared__ __align__(16) float h_lds[HID];           // 8 KB
    const int tid = threadIdx.x;
    const int lane = tid & 63;
    const int w = tid >> 6;                              // 0..7
    const int b = blockIdx.x;                            // 0..255
    const int j = b * 8 + w;                             // hidden unit

    // --- load h-part weights into registers ---
    f32x4 wv[32];                                        // [g*8+q]
    {
        const float* Wp[4] = {Wf, Wi, Wo, Wc};
        #pragma unroll
        for (int g = 0; g < 4; ++g) {
            const float* src = Wp[g] + (size_t)j * DIN + EMB;
            #pragma unroll
            for (int q = 0; q < 8; ++q)
                wv[g * 8 + q] = *(const f32x4*)(src + q * 256 + lane * 4);
        }
    }
    PIN_WEIGHTS(wv);

    const float bias0 = bfv[j], bias1 = biv[j], bias2 = bov[j], bias3 = bcv[j];

    float zx0 = bf2f(Zx[(size_t)0 * R4 + 0 * HID + j]);
    float zx1 = bf2f(Zx[(size_t)0 * R4 + 1 * HID + j]);
    float zx2 = bf2f(Zx[(size_t)0 * R4 + 2 * HID + j]);
    float zx3 = bf2f(Zx[(size_t)0 * R4 + 3 * HID + j]);

    float cst = 0.0f, hlast = 0.0f;
    const int segbase = w * 256 + lane * 4;              // this lane's 4 unit slots

    for (int t = 0; t < SEQLEN; ++t) {
        PIN_WEIGHTS(wv);                                 // loop-carried residency constraint

        // --- issue next step's Zx loads FIRST (drained inside the poll) ---
        float nzx0 = 0.f, nzx1 = 0.f, nzx2 = 0.f, nzx3 = 0.f;
        if (t + 1 < SEQLEN) {
            const size_t base = (size_t)(t + 1) * R4 + j;
            nzx0 = bf2f(Zx[base]);           nzx1 = bf2f(Zx[base + HID]);
            nzx2 = bf2f(Zx[base + 2 * HID]); nzx3 = bf2f(Zx[base + 3 * HID]);
        }

        // --- poll + stage h_{t-1} segment (256 floats per wave) into LDS ---
        if (t == 0) {
            *(f32x4*)&h_lds[segbase] = (f32x4){0.f, 0.f, 0.f, 0.f};
        } else {
            const unsigned tag = (unsigned)(t & 15);
            const unsigned* S = sync + (size_t)(t & 1) * HID + segbase;
            u32x4 v;
            for (;;) {
                v = llc_load4(S);
                const bool ok = ((v[0] & 15u) == tag) & ((v[1] & 15u) == tag) &
                                ((v[2] & 15u) == tag) & ((v[3] & 15u) == tag);
                if (__all((int)ok)) break;
            }
            f32x4 hv;
            hv[0] = __uint_as_float(v[0]); hv[1] = __uint_as_float(v[1]);
            hv[2] = __uint_as_float(v[2]); hv[3] = __uint_as_float(v[3]);
            *(f32x4*)&h_lds[segbase] = hv;
        }
        __syncthreads();                                  // bar#1

        // --- matvec: 128 FMAs/lane, 4 independent accumulator chains ---
        float a0 = 0.f, a1 = 0.f, a2 = 0.f, a3 = 0.f;
        #pragma unroll
        for (int q = 0; q < 8; ++q) {
            const f32x4 hv = *(const f32x4*)&h_lds[q * 256 + lane * 4];
            #pragma unroll
            for (int u = 0; u < 4; ++u) {
                a0 = fmaf(wv[0 * 8 + q][u], hv[u], a0);
                a1 = fmaf(wv[1 * 8 + q][u], hv[u], a1);
                a2 = fmaf(wv[2 * 8 + q][u], hv[u], a2);
                a3 = fmaf(wv[3 * 8 + q][u], hv[u], a3);
            }
        }

        // --- reduce across the 64 lanes ---
        #pragma unroll
        for (int off = 32; off; off >>= 1) {
            a0 += __shfl_xor(a0, off, 64);
            a1 += __shfl_xor(a1, off, 64);
            a2 += __shfl_xor(a2, off, 64);
            a3 += __shfl_xor(a3, off, 64);
        }

        // --- gates (all lanes redundantly; lane0 publishes) ---
        const float zf = zx0 + bias0 + a0;
        const float zi = zx1 + bias1 + a1;
        const float zo = zx2 + bias2 + a2;
        const float zc = zx3 + bias3 + a3;
        const float fg = sigmoid_fast(zf);
        const float ig = sigmoid_fast(zi);
        const float og = sigmoid_fast(zo);
        const float ct = tanh_fast(zc);
        cst = fg * cst + ig * ct;
        const float hn = og * tanh_fast(cst);
        hlast = hn;

        __syncthreads();                                  // bar#2: all h_lds reads done
        if (lane == 0) {
            const unsigned pw = (__float_as_uint(hn) & ~15u) | ((unsigned)(t + 1) & 15u);
            llc_store(&sync[(size_t)((t + 1) & 1) * HID + j], pw);
            Hmat[(size_t)t * HID + j] = hn;               // acks drain in next poll
        }

        zx0 = nzx0; zx1 = nzx1; zx2 = nzx2; zx3 = nzx3;
    }

    if (lane == 0) { outH[j] = hlast; outC[j] = cst; }
}

// ---------------- out = Hmat @ Wout^T + bout ----------------
__global__ __launch_bounds__(256) void out_gemm(const float* __restrict__ H,
                                                const float* __restrict__ Wout,
                                                const float* __restrict__ bout,
                                                float* __restrict__ out) {
    __shared__ float Hs[4][HID];                         // 32 KB
    const int t0 = blockIdx.x * 4;
    const int tid = threadIdx.x;
    {
        const float4* src = (const float4*)(H + (size_t)t0 * HID);
        float4* dst = (float4*)Hs;
        #pragma unroll
        for (int i = tid; i < 4 * HID / 4; i += 256) dst[i] = src[i];
    }
    __syncthreads();
    const int w = tid >> 6, lane = tid & 63;
    for (int ch = w; ch < NCHARS; ch += 4) {
        const float* wrow = Wout + (size_t)ch * HID;
        float acc0 = 0.f, acc1 = 0.f, acc2 = 0.f, acc3 = 0.f;
        #pragma unroll
        for (int q = 0; q < 8; ++q) {
            const int k = q * 256 + lane * 4;
            const float4 wvv = *(const float4*)(wrow + k);
            const float4 h0 = *(const float4*)&Hs[0][k];
            const float4 h1 = *(const float4*)&Hs[1][k];
            const float4 h2 = *(const float4*)&Hs[2][k];
            const float4 h3 = *(const float4*)&Hs[3][k];
            acc0 = fmaf(wvv.x, h0.x, acc0); acc0 = fmaf(wvv.y, h0.y, acc0);
            acc0 = fmaf(wvv.z, h0.z, acc0); acc0 = fmaf(wvv.w, h0.w, acc0);
            acc1 = fmaf(wvv.x, h1.x, acc1); acc1 = fmaf(wvv.y, h1.y, acc1);
            acc1 = fmaf(wvv.z, h1.z, acc1); acc1 = fmaf(wvv.w, h1.w, acc1);
            acc2 = fmaf(wvv.x, h2.x, acc2); acc2 = fmaf(wvv.y, h2.y, acc2);
            acc2 = fmaf(wvv.z, h2.z, acc2); acc2 = fmaf(wvv.w, h2.w, acc2);
            acc3 = fmaf(wvv.x, h3.x, acc3); acc3 = fmaf(wvv.y, h3.y, acc3);
            acc3 = fmaf(wvv.z, h3.z, acc3); acc3 = fmaf(wvv.w, h3.w, acc3);
        }
        #pragma unroll
        for (int off = 32; off; off >>= 1) {
            acc0 += __shfl_xor(acc0, off, 64);
            acc1 += __shfl_xor(acc1, off, 64);
            acc2 += __shfl_xor(acc2, off, 64);
            acc3 += __shfl_xor(acc3, off, 64);
        }
        if (lane == 0) {
            const float bb = bout[ch];
            out[(size_t)(t0 + 0) * NCHARS + ch] = acc0 + bb;
            out[(size_t)(t0 + 1) * NCHARS + ch] = acc1 + bb;
            out[(size_t)(t0 + 2) * NCHARS + ch] = acc2 + bb;
            out[(size_t)(t0 + 3) * NCHARS + ch] = acc3 + bb;
        }
    }
}

extern "C" void kernel_launch(void* const* d_in, const int* in_sizes, int n_in,
                              void* d_out, int out_size, void* d_ws, size_t ws_size,
                              hipStream_t stream) {
    (void)in_sizes; (void)n_in; (void)out_size; (void)ws_size;
    const int*   seq  = (const int*)  d_in[0];
    const float* emb  = (const float*)d_in[1];
    const float* Wf   = (const float*)d_in[2];
    const float* bfv  = (const float*)d_in[3];
    const float* Wi   = (const float*)d_in[4];
    const float* biv  = (const float*)d_in[5];
    const float* Wo   = (const float*)d_in[6];
    const float* bov  = (const float*)d_in[7];
    const float* Wc   = (const float*)d_in[8];
    const float* bcv  = (const float*)d_in[9];
    const float* Wout = (const float*)d_in[10];
    const float* bout = (const float*)d_in[11];
    float* out = (float*)d_out;

    char* ws = (char*)d_ws;
    size_t off = 0;
    unsigned short* Zx = (unsigned short*)(ws + off);  off += (size_t)SEQLEN * R4 * 2;    // 128 MB
    float* Hm = (float*)(ws + off);                    off += (size_t)SEQLEN * HID * 4;   // 64 MB
    unsigned short* Abf = (unsigned short*)(ws + off); off += (size_t)SEQLEN * EMB * 2;   // 16 MB
    unsigned short* Bbf = (unsigned short*)(ws + off); off += (size_t)R4 * EMB * 2;       // 16 MB
    unsigned* sync = (unsigned*)(ws + off);            off += (size_t)2 * HID * 4;        // 16 KB
    // no memset needed: tag nibble of 0xAA poison (0xA) never matches first tags {1,2}

    prep_a<<<SEQLEN, 256, 0, stream>>>(seq, emb, Abf);
    prep_b<<<R4, 256, 0, stream>>>(Wf, Wi, Wo, Wc, Bbf);

    dim3 gg(R4 / 128, SEQLEN / 128);
    gemm_zx<<<gg, 256, 0, stream>>>(Abf, Bbf, Zx);

    lstm_seq<<<256, 512, 0, stream>>>(Wf, Wi, Wo, Wc, bfv, biv, bov, bcv,
                                      Zx, Hm, sync,
                                      out + (size_t)SEQLEN * NCHARS,
                                      out + (size_t)SEQLEN * NCHARS + HID);

    out_gemm<<<SEQLEN / 4, 256, 0, stream>>>(Hm, Wout, bout, out);
}